// Round 2
// baseline (37721.686 us; speedup 1.0000x reference)
//
#include <hip/hip_runtime.h>
#include <math.h>

#define NB   16    // batch
#define TE   256   // T_ENC
#define TD   200   // T_DEC
#define EE   512   // encoder dim
#define ATT  128
#define PREN 256
#define HH   1024
#define NMEL 80
#define NLOC 32
#define KWW  31
#define PADW 15

// workspace offsets (in floats)
#define OFF_X2   0                        // [TD][NB][PREN]  prenet output
#define OFF_PE   (OFF_X2 + TD*NB*PREN)    // [NB][TE][ATT]   processed encoder
#define OFF_AWC  (OFF_PE + NB*TE*ATT)     // [NB][TE]        cumulative attn
#define OFF_EN   (OFF_AWC + NB*TE)        // [NB][TE]        energies
#define OFF_Q    (OFF_EN + NB*TE)         // [NB][ATT]       query proj
#define OFF_CTX  (OFF_Q + NB*ATT)         // [NB][EE]        context
#define OFF_H1   (OFF_CTX + NB*EE)        // [NB][HH]
#define OFF_H2   (OFF_H1 + NB*HH)        // [NB][HH]
#define OFF_BAR  (OFF_H2 + NB*HH)        // barrier state, 1024 uints

#define SCOPE __HIP_MEMORY_SCOPE_AGENT

__device__ __forceinline__ float sigmf(float x) { return 1.0f / (1.0f + expf(-x)); }
__device__ __forceinline__ float dot4(float4 a, float4 b) {
  return a.x*b.x + a.y*b.y + a.z*b.z + a.w*b.w;
}

// ---- manual device-scope barriers (no cooperative launch API) ----
// bar layout (uints): [xg*32]=local cnt, [xg*32+16]=local gen (xg=0..7)
//                     [256]=global cnt, [272]=global gen
//                     [512+b*32]=batch cnt, [512+b*32+16]=batch gen (b=0..15)
__device__ __forceinline__ void bar_generic(unsigned* cnt, unsigned* gen, unsigned n) {
  __syncthreads();
  if (threadIdx.x == 0) {
    unsigned g = __hip_atomic_load(gen, __ATOMIC_RELAXED, SCOPE);
    if (__hip_atomic_fetch_add(cnt, 1u, __ATOMIC_ACQ_REL, SCOPE) == n - 1u) {
      __hip_atomic_store(cnt, 0u, __ATOMIC_RELAXED, SCOPE);
      __hip_atomic_fetch_add(gen, 1u, __ATOMIC_ACQ_REL, SCOPE);
    } else {
      while (__hip_atomic_load(gen, __ATOMIC_ACQUIRE, SCOPE) == g)
        __builtin_amdgcn_s_sleep(1);
    }
  }
  __syncthreads();
}

__device__ __forceinline__ void gbar(unsigned* bar) {
  __syncthreads();
  if (threadIdx.x == 0) {
    const unsigned xg = blockIdx.x & 7;
    unsigned* lc = bar + xg * 32;
    unsigned* lg = bar + xg * 32 + 16;
    unsigned lgen = __hip_atomic_load(lg, __ATOMIC_RELAXED, SCOPE);
    if (__hip_atomic_fetch_add(lc, 1u, __ATOMIC_ACQ_REL, SCOPE) == 31u) {
      unsigned* gc = bar + 256;
      unsigned* gg = bar + 272;
      unsigned ggen = __hip_atomic_load(gg, __ATOMIC_RELAXED, SCOPE);
      __hip_atomic_store(lc, 0u, __ATOMIC_RELAXED, SCOPE);
      if (__hip_atomic_fetch_add(gc, 1u, __ATOMIC_ACQ_REL, SCOPE) == 7u) {
        __hip_atomic_store(gc, 0u, __ATOMIC_RELAXED, SCOPE);
        __hip_atomic_fetch_add(gg, 1u, __ATOMIC_ACQ_REL, SCOPE);
      } else {
        while (__hip_atomic_load(gg, __ATOMIC_ACQUIRE, SCOPE) == ggen)
          __builtin_amdgcn_s_sleep(1);
      }
      __hip_atomic_fetch_add(lg, 1u, __ATOMIC_ACQ_REL, SCOPE);
    } else {
      while (__hip_atomic_load(lg, __ATOMIC_ACQUIRE, SCOPE) == lgen)
        __builtin_amdgcn_s_sleep(1);
    }
  }
  __syncthreads();
}

__device__ __forceinline__ void lbar(unsigned* bar, int b) {
  bar_generic(bar + 512 + b * 32, bar + 512 + b * 32 + 16, 16u);
}

// ---------------- init: zero awc, qv, barrier state ----------------
__global__ void k_init(float* __restrict__ ws) {
  const int tid = threadIdx.x;
  float* awc = ws + OFF_AWC;
  float* qv  = ws + OFF_Q;
  unsigned* bar = (unsigned*)(ws + OFF_BAR);
  for (int i = tid; i < NB*TE; i += 256) awc[i] = 0.0f;
  for (int i = tid; i < NB*ATT; i += 256) qv[i] = 0.0f;
  for (int i = tid; i < 1024; i += 256) bar[i] = 0u;
}

// ---------------- prenet: x2 = relu(relu(prev_mel@W1^T)@W2^T) ----------------
__global__ void k_prenet(const float* __restrict__ mels,  // [NB][TD][NMEL]
                         const float* __restrict__ w1,    // [PREN][NMEL]
                         const float* __restrict__ w2,    // [PREN][PREN]
                         float* __restrict__ x2) {        // [TD][NB][PREN]
  const int t = blockIdx.x >> 4;
  const int b = blockIdx.x & 15;
  const int j = threadIdx.x;   // 0..255
  __shared__ float s_in[NMEL];
  __shared__ float s_x1[PREN];
  if (j < NMEL) s_in[j] = (t == 0) ? 0.0f : mels[(b*TD + (t-1))*NMEL + j];
  __syncthreads();
  float a1 = 0.0f;
  #pragma unroll 8
  for (int k = 0; k < NMEL; ++k) a1 += s_in[k] * w1[j*NMEL + k];
  s_x1[j] = fmaxf(a1, 0.0f);
  __syncthreads();
  float a2 = 0.0f;
  #pragma unroll 8
  for (int k = 0; k < PREN; ++k) a2 += s_x1[k] * w2[j*PREN + k];
  x2[(t*NB + b)*PREN + j] = fmaxf(a2, 0.0f);
}

// ---------------- processed encoder: pe = enc @ enc_proj_w^T ----------------
__global__ void k_procenc(const float* __restrict__ enc,  // [NB][TE][EE]
                          const float* __restrict__ w,    // [ATT][EE]
                          float* __restrict__ pe) {       // [NB][TE][ATT]
  const int bt = blockIdx.x;       // b*TE + t
  const int a = threadIdx.x;       // 0..127
  __shared__ float s_e[EE];
  for (int k = a; k < EE; k += 128) s_e[k] = enc[bt*EE + k];
  __syncthreads();
  float acc = 0.0f;
  #pragma unroll 8
  for (int k = 0; k < EE; ++k) acc += s_e[k] * w[a*EE + k];
  pe[bt*ATT + a] = acc;
}

// ---------------- main sequential decoder loop (manual grid sync) ----------------
__global__ void __launch_bounds__(256, 1) k_main(
    const float* __restrict__ enc,
    const float* __restrict__ lstm_proj_w,   // [ATT][HH]
    const float* __restrict__ loc_conv_w,    // [NLOC][1][KWW]
    const float* __restrict__ loc_conv_b,    // [NLOC]
    const float* __restrict__ loc_dense_w,   // [ATT][NLOC]
    const float* __restrict__ loc_dense_b,   // [ATT]
    const float* __restrict__ e_w,           // [1][ATT]
    const float* __restrict__ e_b,           // [1]
    const float* __restrict__ w_ih0,         // [4H][PREN+EE]
    const float* __restrict__ b_ih0,
    const float* __restrict__ b_hh0,
    const float* __restrict__ w_ih1,         // [4H][HH]
    const float* __restrict__ b_ih1,
    const float* __restrict__ b_hh1,
    const float* __restrict__ proj_w,        // [NMEL][HH+EE]
    const float* __restrict__ proj_b,
    const float* __restrict__ stop_w,        // [1][HH+EE]
    const float* __restrict__ stop_b,
    const int*   __restrict__ text_len,      // [NB]
    float* __restrict__ ws,
    float* __restrict__ out) {
  const int bid = blockIdx.x;   // 0..255
  const int tid = threadIdx.x;  // 0..255

  float* x2  = ws + OFF_X2;
  float* pe  = ws + OFF_PE;
  float* awc = ws + OFF_AWC;
  float* en  = ws + OFF_EN;
  float* qv  = ws + OFF_Q;
  float* ctx = ws + OFF_CTX;
  float* h1  = ws + OFF_H1;
  float* h2  = ws + OFF_H2;
  unsigned* bar = (unsigned*)(ws + OFF_BAR);

  __shared__ float s_ldw[NLOC * ATT];             // loc_dense_w transposed [c][a]
  __shared__ __align__(16) float s_buf[2048];

  for (int i = tid; i < NLOC*ATT; i += 256) {
    int c = i >> 7, a = i & 127;
    s_ldw[i] = loc_dense_w[a*NLOC + c];
  }
  // batch-group id for P1/P2/P5: groups {b, b+16, ..., b+240} share bid%8
  const int b_grp = bid & 15;
  const int sub   = bid >> 4;

  gbar(bar);  // ensure k_init state + s_ldw of all blocks ready (also x2/pe via stream order)

  for (int t = 0; t < TD; ++t) {
    // ===== P1: energies en[b][tt] = sum_a tanh(q+loc_dense+pe)*e_w + e_b =====
    {
      const int b = b_grp;
      const int chunk = sub;
      const int tl = tid >> 4;   // 0..15
      const int j = tid & 15;    // 0..15
      const int tt = chunk*16 + tl;
      if (tid < ATT) s_buf[tid] = qv[b*ATT + tid];
      else           s_buf[tid] = e_w[tid - ATT];
      __syncthreads();
      const float* awcb = awc + b*TE;
      #pragma unroll
      for (int cc = 0; cc < 2; ++cc) {
        const int c = j + cc*16;
        float acc = loc_conv_b[c];
        #pragma unroll 8
        for (int k = 0; k < KWW; ++k) {
          const int ti = tt + k - PADW;
          if (ti >= 0 && ti < TE) acc += awcb[ti] * loc_conv_w[c*KWW + k];
        }
        s_buf[256 + tl*33 + c] = acc;   // stride 33 kills bank conflicts
      }
      __syncthreads();
      float acc = 0.0f;
      const float* peb = pe + (b*TE + tt)*ATT;
      const float* locp = s_buf + 256 + tl*33;
      for (int s = 0; s < 8; ++s) {
        const int a = s*16 + j;
        float term = s_buf[a] + loc_dense_b[a] + peb[a];
        float d = 0.0f;
        #pragma unroll 8
        for (int c = 0; c < NLOC; ++c) d += locp[c] * s_ldw[c*ATT + a];
        acc += tanhf(term + d) * s_buf[ATT + a];
      }
      acc += __shfl_down(acc, 8, 16);
      acc += __shfl_down(acc, 4, 16);
      acc += __shfl_down(acc, 2, 16);
      acc += __shfl_down(acc, 1, 16);
      if (j == 0) {
        float ev = acc + e_b[0];
        if (tt >= text_len[b]) ev = -1e9f;
        en[b*TE + tt] = ev;
      }
    }
    lbar(bar, b_grp);
    // ===== P2: softmax (redundant per e-chunk) + awc update + ctx =====
    {
      const int b = b_grp;
      const int ec = sub;
      const float ev = en[b*TE + tid];
      s_buf[256 + tid] = ev;
      __syncthreads();
      for (int d = 128; d > 0; d >>= 1) {
        if (tid < d) s_buf[256+tid] = fmaxf(s_buf[256+tid], s_buf[256+tid+d]);
        __syncthreads();
      }
      const float mx = s_buf[256];
      __syncthreads();
      const float p = expf(ev - mx);
      s_buf[256 + tid] = p;
      __syncthreads();
      for (int d = 128; d > 0; d >>= 1) {
        if (tid < d) s_buf[256+tid] += s_buf[256+tid+d];
        __syncthreads();
      }
      const float aw = p / s_buf[256];
      s_buf[tid] = aw;                       // aw row in LDS
      if (ec == 0) awc[b*TE + tid] += aw;
      __syncthreads();
      // ctx chunk: this block computes 32 e's (as 8 float4) for batch b
      const int e4 = tid >> 5;   // 0..7
      const int ts = tid & 31;   // 0..31
      const float4* enc4 = (const float4*)(enc + (size_t)b*TE*EE);
      float4 a4 = make_float4(0.f,0.f,0.f,0.f);
      #pragma unroll
      for (int i = 0; i < 8; ++i) {
        const int tt2 = ts + 32*i;
        const float awv = s_buf[tt2];
        const float4 ev4 = enc4[tt2*(EE/4) + ec*8 + e4];
        a4.x += awv*ev4.x; a4.y += awv*ev4.y; a4.z += awv*ev4.z; a4.w += awv*ev4.w;
      }
      for (int d = 16; d > 0; d >>= 1) {
        a4.x += __shfl_down(a4.x, d, 32);
        a4.y += __shfl_down(a4.y, d, 32);
        a4.z += __shfl_down(a4.z, d, 32);
        a4.w += __shfl_down(a4.w, d, 32);
      }
      if (ts == 0) ((float4*)ctx)[b*(EE/4) + ec*8 + e4] = a4;
    }
    gbar(bar);
    // ===== P3: LSTM0  h1 = sig(o)*tanh(sig(i)*tanh(g)), gates i,g,o only =====
    {
      const int h0 = bid * 4;     // 4 h per block
      const int b = tid >> 4;     // 0..15
      const int kc = tid & 15;    // k-split 16
      float acc[12];
      #pragma unroll
      for (int z = 0; z < 12; ++z) acc[z] = 0.0f;
      const float4* x4 = (const float4*)(x2 + (size_t)(t*NB + b)*PREN);
      const float4* c4 = (const float4*)(ctx + b*EE);
      const float4* w4 = (const float4*)w_ih0;   // row stride 192 float4
      #pragma unroll
      for (int i = 0; i < 4; ++i) {              // x part (256 floats)
        const int kf = kc*4 + i;
        const float4 lv = x4[kf];
        #pragma unroll
        for (int h = 0; h < 4; ++h) {
          acc[h*3+0] += dot4(lv, w4[(h0+h)*192 + kf]);
          acc[h*3+1] += dot4(lv, w4[(2048+h0+h)*192 + kf]);
          acc[h*3+2] += dot4(lv, w4[(3072+h0+h)*192 + kf]);
        }
      }
      #pragma unroll 4
      for (int i = 0; i < 8; ++i) {              // ctx part (512 floats)
        const int kf = kc*8 + i;
        const float4 lv = c4[kf];
        #pragma unroll
        for (int h = 0; h < 4; ++h) {
          acc[h*3+0] += dot4(lv, w4[(h0+h)*192 + 64 + kf]);
          acc[h*3+1] += dot4(lv, w4[(2048+h0+h)*192 + 64 + kf]);
          acc[h*3+2] += dot4(lv, w4[(3072+h0+h)*192 + 64 + kf]);
        }
      }
      #pragma unroll
      for (int z = 0; z < 12; ++z) {
        float v = acc[z];
        v += __shfl_down(v, 8, 16);
        v += __shfl_down(v, 4, 16);
        v += __shfl_down(v, 2, 16);
        v += __shfl_down(v, 1, 16);
        acc[z] = v;
      }
      if (kc == 0) {
        #pragma unroll
        for (int h = 0; h < 4; ++h) {
          const int hh = h0 + h;
          const float gi = acc[h*3+0] + b_ih0[hh]      + b_hh0[hh];
          const float gg = acc[h*3+1] + b_ih0[2048+hh] + b_hh0[2048+hh];
          const float go = acc[h*3+2] + b_ih0[3072+hh] + b_hh0[3072+hh];
          const float c = sigmf(gi) * tanhf(gg);
          h1[b*HH + hh] = sigmf(go) * tanhf(c);
        }
      }
    }
    gbar(bar);
    // ===== P4: LSTM1 =====
    {
      const int h0 = bid * 4;
      const int b = tid >> 4;
      const int kc = tid & 15;
      float acc[12];
      #pragma unroll
      for (int z = 0; z < 12; ++z) acc[z] = 0.0f;
      const float4* hv4 = (const float4*)(h1 + b*HH);
      const float4* w4 = (const float4*)w_ih1;   // row stride 256 float4
      #pragma unroll 4
      for (int i = 0; i < 16; ++i) {             // 1024 floats
        const int kf = kc*16 + i;
        const float4 lv = hv4[kf];
        #pragma unroll
        for (int h = 0; h < 4; ++h) {
          acc[h*3+0] += dot4(lv, w4[(h0+h)*256 + kf]);
          acc[h*3+1] += dot4(lv, w4[(2048+h0+h)*256 + kf]);
          acc[h*3+2] += dot4(lv, w4[(3072+h0+h)*256 + kf]);
        }
      }
      #pragma unroll
      for (int z = 0; z < 12; ++z) {
        float v = acc[z];
        v += __shfl_down(v, 8, 16);
        v += __shfl_down(v, 4, 16);
        v += __shfl_down(v, 2, 16);
        v += __shfl_down(v, 1, 16);
        acc[z] = v;
      }
      if (kc == 0) {
        #pragma unroll
        for (int h = 0; h < 4; ++h) {
          const int hh = h0 + h;
          const float gi = acc[h*3+0] + b_ih1[hh]      + b_hh1[hh];
          const float gg = acc[h*3+1] + b_ih1[2048+hh] + b_hh1[2048+hh];
          const float go = acc[h*3+2] + b_ih1[3072+hh] + b_hh1[3072+hh];
          const float c = sigmf(gi) * tanhf(gg);
          h2[b*HH + hh] = sigmf(go) * tanhf(c);
        }
      }
    }
    gbar(bar);
    // ===== P5: q = h2@lstm_proj_w^T ; mel/stop = [h2,ctx]@proj^T =====
    {
      const int b = b_grp;
      const int part = sub;
      for (int i = tid; i < HH + EE; i += 256)
        s_buf[i] = (i < HH) ? h2[b*HH + i] : ctx[b*EE + (i - HH)];
      __syncthreads();
      const int ol = tid >> 4;   // 0..15
      const int kc = tid & 15;
      const float4* s4 = (const float4*)s_buf;
      if (part < 8) {
        const int a = part*16 + ol;               // 0..127
        const float4* w4 = (const float4*)(lstm_proj_w + a*HH);
        float acc = 0.0f;
        #pragma unroll 4
        for (int i = 0; i < 16; ++i) {
          const int kf = kc*4 + (i & 3) + (i >> 2)*64;  // strided over 256 f4
          acc += dot4(s4[kf], w4[kf]);
        }
        acc += __shfl_down(acc, 8, 16);
        acc += __shfl_down(acc, 4, 16);
        acc += __shfl_down(acc, 2, 16);
        acc += __shfl_down(acc, 1, 16);
        if (kc == 0) qv[b*ATT + a] = acc;
      } else {
        const int m = (part - 8)*11 + ol;         // 0..87, need 0..80
        if (ol < 11 && m < 81) {
          const float* wrow = (m < NMEL) ? (proj_w + m*(HH+EE)) : stop_w;
          const float4* w4 = (const float4*)wrow;
          float acc = 0.0f;
          #pragma unroll 4
          for (int i = 0; i < 24; ++i) {
            const int kf = kc + 16*i;             // 384 float4 = 1536 floats
            acc += dot4(s4[kf], w4[kf]);
          }
          acc += __shfl_down(acc, 8, 16);
          acc += __shfl_down(acc, 4, 16);
          acc += __shfl_down(acc, 2, 16);
          acc += __shfl_down(acc, 1, 16);
          if (kc == 0) {
            if (m < NMEL) out[(b*TD + t)*NMEL + m] = acc + proj_b[m];
            else          out[NB*TD*NMEL + b*TD + t] = acc + stop_b[0];
          }
        }
      }
    }
    lbar(bar, b_grp);
  }
}

extern "C" void kernel_launch(void* const* d_in, const int* in_sizes, int n_in,
                              void* d_out, int out_size, void* d_ws, size_t ws_size,
                              hipStream_t stream) {
  (void)in_sizes; (void)n_in; (void)out_size; (void)ws_size;
  const float* enc         = (const float*)d_in[0];
  const float* mels        = (const float*)d_in[1];
  const float* enc_proj_w  = (const float*)d_in[2];
  const float* lstm_proj_w = (const float*)d_in[3];
  const float* loc_conv_w  = (const float*)d_in[4];
  const float* loc_conv_b  = (const float*)d_in[5];
  const float* loc_dense_w = (const float*)d_in[6];
  const float* loc_dense_b = (const float*)d_in[7];
  const float* e_w         = (const float*)d_in[8];
  const float* e_b         = (const float*)d_in[9];
  const float* prenet1_w   = (const float*)d_in[10];
  const float* prenet2_w   = (const float*)d_in[11];
  const float* w_ih0       = (const float*)d_in[12];
  const float* b_ih0       = (const float*)d_in[14];
  const float* b_hh0       = (const float*)d_in[15];
  const float* w_ih1       = (const float*)d_in[16];
  const float* b_ih1       = (const float*)d_in[18];
  const float* b_hh1       = (const float*)d_in[19];
  const float* proj_w      = (const float*)d_in[20];
  const float* proj_b      = (const float*)d_in[21];
  const float* stop_w      = (const float*)d_in[22];
  const float* stop_b      = (const float*)d_in[23];
  const int*   text_len    = (const int*)d_in[24];
  float* ws  = (float*)d_ws;
  float* out = (float*)d_out;

  k_init<<<dim3(1), dim3(256), 0, stream>>>(ws);
  k_prenet<<<dim3(TD*NB), dim3(256), 0, stream>>>(mels, prenet1_w, prenet2_w, ws + OFF_X2);
  k_procenc<<<dim3(NB*TE), dim3(128), 0, stream>>>(enc, enc_proj_w, ws + OFF_PE);

  k_main<<<dim3(256), dim3(256), 0, stream>>>(
      enc, lstm_proj_w, loc_conv_w, loc_conv_b, loc_dense_w, loc_dense_b,
      e_w, e_b, w_ih0, b_ih0, b_hh0, w_ih1, b_ih1, b_hh1,
      proj_w, proj_b, stop_w, stop_b, text_len, ws, out);
}

// Round 3
// 27088.000 us; speedup vs baseline: 1.3926x; 1.3926x over previous
//
#include <hip/hip_runtime.h>
#include <math.h>

#define NB   16    // batch
#define TE   256   // T_ENC
#define TD   200   // T_DEC
#define EE   512   // encoder dim
#define ATT  128
#define PREN 256
#define HH   1024
#define NMEL 80
#define NLOC 32
#define KWW  31
#define PADW 15

// workspace offsets (in floats)
#define OFF_X2   0                        // [TD][NB][PREN]  prenet output
#define OFF_PE   (OFF_X2 + TD*NB*PREN)    // [NB][TE][ATT]   processed encoder
#define OFF_AWC  (OFF_PE + NB*TE*ATT)     // [NB][TE]        cumulative attn
#define OFF_EN   (OFF_AWC + NB*TE)        // [NB][TE]        energies
#define OFF_Q    (OFF_EN + NB*TE)         // [NB][ATT]       query proj
#define OFF_CTX  (OFF_Q + NB*ATT)         // [NB][EE]        context
#define OFF_H1   (OFF_CTX + NB*EE)        // [NB][HH]
#define OFF_H2   (OFF_H1 + NB*HH)        // [NB][HH]
#define OFF_BAR  (OFF_H2 + NB*HH)        // barrier state, 1024 uints

// dynamic LDS: 12 rows x 768 (w_ih0 slice) + 12 rows x 1024 (w_ih1 slice)
#define LW0_F4   (12*192)
#define LW1_F4   (12*256)
#define DYN_BYTES ((LW0_F4 + LW1_F4) * 16)

#define SCOPE __HIP_MEMORY_SCOPE_AGENT

__device__ __forceinline__ float sigmf(float x) { return 1.0f / (1.0f + expf(-x)); }
__device__ __forceinline__ float dot4(float4 a, float4 b) {
  return a.x*b.x + a.y*b.y + a.z*b.z + a.w*b.w;
}

// ---- manual device-scope barriers (no cooperative launch API) ----
__device__ __forceinline__ void bar_generic(unsigned* cnt, unsigned* gen, unsigned n) {
  __syncthreads();
  if (threadIdx.x == 0) {
    unsigned g = __hip_atomic_load(gen, __ATOMIC_RELAXED, SCOPE);
    if (__hip_atomic_fetch_add(cnt, 1u, __ATOMIC_ACQ_REL, SCOPE) == n - 1u) {
      __hip_atomic_store(cnt, 0u, __ATOMIC_RELAXED, SCOPE);
      __hip_atomic_fetch_add(gen, 1u, __ATOMIC_ACQ_REL, SCOPE);
    } else {
      while (__hip_atomic_load(gen, __ATOMIC_ACQUIRE, SCOPE) == g)
        __builtin_amdgcn_s_sleep(1);
    }
  }
  __syncthreads();
}

__device__ __forceinline__ void gbar(unsigned* bar) {
  __syncthreads();
  if (threadIdx.x == 0) {
    const unsigned xg = blockIdx.x & 7;
    unsigned* lc = bar + xg * 32;
    unsigned* lg = bar + xg * 32 + 16;
    unsigned lgen = __hip_atomic_load(lg, __ATOMIC_RELAXED, SCOPE);
    if (__hip_atomic_fetch_add(lc, 1u, __ATOMIC_ACQ_REL, SCOPE) == 31u) {
      unsigned* gc = bar + 256;
      unsigned* gg = bar + 272;
      unsigned ggen = __hip_atomic_load(gg, __ATOMIC_RELAXED, SCOPE);
      __hip_atomic_store(lc, 0u, __ATOMIC_RELAXED, SCOPE);
      if (__hip_atomic_fetch_add(gc, 1u, __ATOMIC_ACQ_REL, SCOPE) == 7u) {
        __hip_atomic_store(gc, 0u, __ATOMIC_RELAXED, SCOPE);
        __hip_atomic_fetch_add(gg, 1u, __ATOMIC_ACQ_REL, SCOPE);
      } else {
        while (__hip_atomic_load(gg, __ATOMIC_ACQUIRE, SCOPE) == ggen)
          __builtin_amdgcn_s_sleep(1);
      }
      __hip_atomic_fetch_add(lg, 1u, __ATOMIC_ACQ_REL, SCOPE);
    } else {
      while (__hip_atomic_load(lg, __ATOMIC_ACQUIRE, SCOPE) == lgen)
        __builtin_amdgcn_s_sleep(1);
    }
  }
  __syncthreads();
}

__device__ __forceinline__ void lbar(unsigned* bar, int b) {
  bar_generic(bar + 512 + b * 32, bar + 512 + b * 32 + 16, 16u);
}

// ---------------- init: zero awc, qv, barrier state ----------------
__global__ void k_init(float* __restrict__ ws) {
  const int tid = threadIdx.x;
  float* awc = ws + OFF_AWC;
  float* qv  = ws + OFF_Q;
  unsigned* bar = (unsigned*)(ws + OFF_BAR);
  for (int i = tid; i < NB*TE; i += 256) awc[i] = 0.0f;
  for (int i = tid; i < NB*ATT; i += 256) qv[i] = 0.0f;
  for (int i = tid; i < 1024; i += 256) bar[i] = 0u;
}

// ---------------- prenet: x2 = relu(relu(prev_mel@W1^T)@W2^T) ----------------
__global__ void k_prenet(const float* __restrict__ mels,  // [NB][TD][NMEL]
                         const float* __restrict__ w1,    // [PREN][NMEL]
                         const float* __restrict__ w2,    // [PREN][PREN]
                         float* __restrict__ x2) {        // [TD][NB][PREN]
  const int t = blockIdx.x >> 4;
  const int b = blockIdx.x & 15;
  const int j = threadIdx.x;   // 0..255
  __shared__ float s_in[NMEL];
  __shared__ float s_x1[PREN];
  if (j < NMEL) s_in[j] = (t == 0) ? 0.0f : mels[(b*TD + (t-1))*NMEL + j];
  __syncthreads();
  float a1 = 0.0f;
  #pragma unroll 8
  for (int k = 0; k < NMEL; ++k) a1 += s_in[k] * w1[j*NMEL + k];
  s_x1[j] = fmaxf(a1, 0.0f);
  __syncthreads();
  float a2 = 0.0f;
  #pragma unroll 8
  for (int k = 0; k < PREN; ++k) a2 += s_x1[k] * w2[j*PREN + k];
  x2[(t*NB + b)*PREN + j] = fmaxf(a2, 0.0f);
}

// ---------------- processed encoder: pe = enc @ enc_proj_w^T ----------------
__global__ void k_procenc(const float* __restrict__ enc,  // [NB][TE][EE]
                          const float* __restrict__ w,    // [ATT][EE]
                          float* __restrict__ pe) {       // [NB][TE][ATT]
  const int bt = blockIdx.x;       // b*TE + t
  const int a = threadIdx.x;       // 0..127
  __shared__ float s_e[EE];
  for (int k = a; k < EE; k += 128) s_e[k] = enc[bt*EE + k];
  __syncthreads();
  float acc = 0.0f;
  #pragma unroll 8
  for (int k = 0; k < EE; ++k) acc += s_e[k] * w[a*EE + k];
  pe[bt*ATT + a] = acc;
}

// ---------------- main sequential decoder loop (manual grid sync) ----------------
__global__ void __launch_bounds__(256, 1) k_main(
    const float* __restrict__ enc,
    const float* __restrict__ lstm_proj_w,   // [ATT][HH]
    const float* __restrict__ loc_conv_w,    // [NLOC][1][KWW]
    const float* __restrict__ loc_conv_b,    // [NLOC]
    const float* __restrict__ loc_dense_w,   // [ATT][NLOC]
    const float* __restrict__ loc_dense_b,   // [ATT]
    const float* __restrict__ e_w,           // [1][ATT]
    const float* __restrict__ e_b,           // [1]
    const float* __restrict__ w_ih0,         // [4H][PREN+EE]
    const float* __restrict__ b_ih0,
    const float* __restrict__ b_hh0,
    const float* __restrict__ w_ih1,         // [4H][HH]
    const float* __restrict__ b_ih1,
    const float* __restrict__ b_hh1,
    const float* __restrict__ proj_w,        // [NMEL][HH+EE]
    const float* __restrict__ proj_b,
    const float* __restrict__ stop_w,        // [1][HH+EE]
    const float* __restrict__ stop_b,
    const int*   __restrict__ text_len,      // [NB]
    float* __restrict__ ws,
    float* __restrict__ out) {
  const int bid = blockIdx.x;   // 0..255
  const int tid = threadIdx.x;  // 0..255

  float* x2  = ws + OFF_X2;
  float* pe  = ws + OFF_PE;
  float* awc = ws + OFF_AWC;
  float* en  = ws + OFF_EN;
  float* qv  = ws + OFF_Q;
  float* ctx = ws + OFF_CTX;
  float* h1  = ws + OFF_H1;
  float* h2  = ws + OFF_H2;
  unsigned* bar = (unsigned*)(ws + OFF_BAR);

  __shared__ float s_ldw[NLOC * ATT];             // loc_dense_w transposed [c][a]
  __shared__ __align__(16) float s_buf[2048];
  extern __shared__ __align__(16) float dynlds[]; // lw0[12][768] | lw1[12][1024]
  float4* lw0 = (float4*)dynlds;                  // 12*192 f4
  float4* lw1 = ((float4*)dynlds) + LW0_F4;       // 12*256 f4

  for (int i = tid; i < NLOC*ATT; i += 256) {
    int c = i >> 7, a = i & 127;
    s_ldw[i] = loc_dense_w[a*NLOC + c];
  }
  // stage this block's 12+12 gate rows into LDS (once for all 200 steps)
  // row r = g*4 + h, gate g in {i,g,o} -> global row off {0,2048,3072} + bid*4+h
  {
    const int h0 = bid * 4;
    const float4* w0_4 = (const float4*)w_ih0;   // row stride 192
    const float4* w1_4 = (const float4*)w_ih1;   // row stride 256
    for (int i = tid; i < LW0_F4; i += 256) {
      const int r = i / 192, c = i % 192;
      const int g = r >> 2, h = r & 3;
      const int grow = (g == 0 ? 0 : (g == 1 ? 2048 : 3072)) + h0 + h;
      lw0[i] = w0_4[grow*192 + c];
    }
    for (int i = tid; i < LW1_F4; i += 256) {
      const int r = i >> 8, c = i & 255;
      const int g = r >> 2, h = r & 3;
      const int grow = (g == 0 ? 0 : (g == 1 ? 2048 : 3072)) + h0 + h;
      lw1[i] = w1_4[grow*256 + c];
    }
  }
  // batch-group id for P1/P2/P5: groups {b, b+16, ..., b+240} share bid%8
  const int b_grp = bid & 15;
  const int sub   = bid >> 4;

  gbar(bar);  // k_init state visible; x2/pe ready via stream order

  for (int t = 0; t < TD; ++t) {
    // ===== P1: energies en[b][tt] = sum_a tanh(q+loc_dense+pe)*e_w + e_b =====
    {
      const int b = b_grp;
      const int chunk = sub;
      const int tl = tid >> 4;   // 0..15
      const int j = tid & 15;    // 0..15
      const int tt = chunk*16 + tl;
      if (tid < ATT) s_buf[tid] = qv[b*ATT + tid];
      else           s_buf[tid] = e_w[tid - ATT];
      __syncthreads();
      const float* awcb = awc + b*TE;
      #pragma unroll
      for (int cc = 0; cc < 2; ++cc) {
        const int c = j + cc*16;
        float acc = loc_conv_b[c];
        #pragma unroll 8
        for (int k = 0; k < KWW; ++k) {
          const int ti = tt + k - PADW;
          if (ti >= 0 && ti < TE) acc += awcb[ti] * loc_conv_w[c*KWW + k];
        }
        s_buf[256 + tl*33 + c] = acc;   // stride 33 kills bank conflicts
      }
      __syncthreads();
      float acc = 0.0f;
      const float* peb = pe + (b*TE + tt)*ATT;
      const float* locp = s_buf + 256 + tl*33;
      for (int s = 0; s < 8; ++s) {
        const int a = s*16 + j;
        float term = s_buf[a] + loc_dense_b[a] + peb[a];
        float d = 0.0f;
        #pragma unroll 8
        for (int c = 0; c < NLOC; ++c) d += locp[c] * s_ldw[c*ATT + a];
        acc += tanhf(term + d) * s_buf[ATT + a];
      }
      acc += __shfl_down(acc, 8, 16);
      acc += __shfl_down(acc, 4, 16);
      acc += __shfl_down(acc, 2, 16);
      acc += __shfl_down(acc, 1, 16);
      if (j == 0) {
        float ev = acc + e_b[0];
        if (tt >= text_len[b]) ev = -1e9f;
        en[b*TE + tt] = ev;
      }
    }
    lbar(bar, b_grp);
    // ===== P2: softmax (redundant per e-chunk) + awc update + ctx =====
    {
      const int b = b_grp;
      const int ec = sub;
      const float ev = en[b*TE + tid];
      s_buf[256 + tid] = ev;
      __syncthreads();
      for (int d = 128; d > 0; d >>= 1) {
        if (tid < d) s_buf[256+tid] = fmaxf(s_buf[256+tid], s_buf[256+tid+d]);
        __syncthreads();
      }
      const float mx = s_buf[256];
      __syncthreads();
      const float p = expf(ev - mx);
      s_buf[256 + tid] = p;
      __syncthreads();
      for (int d = 128; d > 0; d >>= 1) {
        if (tid < d) s_buf[256+tid] += s_buf[256+tid+d];
        __syncthreads();
      }
      const float aw = p / s_buf[256];
      s_buf[tid] = aw;                       // aw row in LDS
      if (ec == 0) awc[b*TE + tid] += aw;
      __syncthreads();
      // ctx chunk: this block computes 32 e's (as 8 float4) for batch b
      const int e4 = tid >> 5;   // 0..7
      const int ts = tid & 31;   // 0..31
      const float4* enc4 = (const float4*)(enc + (size_t)b*TE*EE);
      float4 a4 = make_float4(0.f,0.f,0.f,0.f);
      #pragma unroll
      for (int i = 0; i < 8; ++i) {
        const int tt2 = ts + 32*i;
        const float awv = s_buf[tt2];
        const float4 ev4 = enc4[tt2*(EE/4) + ec*8 + e4];
        a4.x += awv*ev4.x; a4.y += awv*ev4.y; a4.z += awv*ev4.z; a4.w += awv*ev4.w;
      }
      for (int d = 16; d > 0; d >>= 1) {
        a4.x += __shfl_down(a4.x, d, 32);
        a4.y += __shfl_down(a4.y, d, 32);
        a4.z += __shfl_down(a4.z, d, 32);
        a4.w += __shfl_down(a4.w, d, 32);
      }
      if (ts == 0) ((float4*)ctx)[b*(EE/4) + ec*8 + e4] = a4;
    }
    gbar(bar);
    // ===== P3: LSTM0  h1 = sig(o)*tanh(sig(i)*tanh(g)); weights in LDS =====
    {
      const int b = tid >> 4;     // 0..15
      const int kc = tid & 15;    // k-split 16
      float acc[12];
      #pragma unroll
      for (int z = 0; z < 12; ++z) acc[z] = 0.0f;
      const float4* x4 = (const float4*)(x2 + (size_t)(t*NB + b)*PREN);
      const float4* c4 = (const float4*)(ctx + b*EE);
      #pragma unroll
      for (int i = 0; i < 4; ++i) {              // x part (64 f4)
        const int kf = kc + 16*i;
        const float4 lv = x4[kf];
        #pragma unroll
        for (int r = 0; r < 12; ++r) acc[r] += dot4(lv, lw0[r*192 + kf]);
      }
      #pragma unroll 2
      for (int i = 0; i < 8; ++i) {              // ctx part (128 f4)
        const int kf = kc + 16*i;
        const float4 lv = c4[kf];
        #pragma unroll
        for (int r = 0; r < 12; ++r) acc[r] += dot4(lv, lw0[r*192 + 64 + kf]);
      }
      #pragma unroll
      for (int z = 0; z < 12; ++z) {
        float v = acc[z];
        v += __shfl_down(v, 8, 16);
        v += __shfl_down(v, 4, 16);
        v += __shfl_down(v, 2, 16);
        v += __shfl_down(v, 1, 16);
        acc[z] = v;
      }
      if (kc == 0) {
        const int h0 = bid * 4;
        #pragma unroll
        for (int h = 0; h < 4; ++h) {
          const int hh = h0 + h;
          const float gi = acc[0 + h] + b_ih0[hh]      + b_hh0[hh];
          const float gg = acc[4 + h] + b_ih0[2048+hh] + b_hh0[2048+hh];
          const float go = acc[8 + h] + b_ih0[3072+hh] + b_hh0[3072+hh];
          const float c = sigmf(gi) * tanhf(gg);
          h1[b*HH + hh] = sigmf(go) * tanhf(c);
        }
      }
    }
    gbar(bar);
    // ===== P4: LSTM1 (weights in LDS) =====
    {
      const int b = tid >> 4;
      const int kc = tid & 15;
      float acc[12];
      #pragma unroll
      for (int z = 0; z < 12; ++z) acc[z] = 0.0f;
      const float4* hv4 = (const float4*)(h1 + b*HH);
      #pragma unroll 4
      for (int i = 0; i < 16; ++i) {             // 256 f4
        const int kf = kc + 16*i;
        const float4 lv = hv4[kf];
        #pragma unroll
        for (int r = 0; r < 12; ++r) acc[r] += dot4(lv, lw1[r*256 + kf]);
      }
      #pragma unroll
      for (int z = 0; z < 12; ++z) {
        float v = acc[z];
        v += __shfl_down(v, 8, 16);
        v += __shfl_down(v, 4, 16);
        v += __shfl_down(v, 2, 16);
        v += __shfl_down(v, 1, 16);
        acc[z] = v;
      }
      if (kc == 0) {
        const int h0 = bid * 4;
        #pragma unroll
        for (int h = 0; h < 4; ++h) {
          const int hh = h0 + h;
          const float gi = acc[0 + h] + b_ih1[hh]      + b_hh1[hh];
          const float gg = acc[4 + h] + b_ih1[2048+hh] + b_hh1[2048+hh];
          const float go = acc[8 + h] + b_ih1[3072+hh] + b_hh1[3072+hh];
          const float c = sigmf(gi) * tanhf(gg);
          h2[b*HH + hh] = sigmf(go) * tanhf(c);
        }
      }
    }
    gbar(bar);
    // ===== P5: q = h2@lstm_proj_w^T ; mel/stop = [h2,ctx]@proj^T =====
    {
      const int b = b_grp;
      const int part = sub;
      for (int i = tid; i < HH + EE; i += 256)
        s_buf[i] = (i < HH) ? h2[b*HH + i] : ctx[b*EE + (i - HH)];
      __syncthreads();
      const int ol = tid >> 4;   // 0..15
      const int kc = tid & 15;
      const float4* s4 = (const float4*)s_buf;
      if (part < 8) {
        const int a = part*16 + ol;               // 0..127
        const float4* w4 = (const float4*)(lstm_proj_w + a*HH);
        float acc = 0.0f;
        #pragma unroll 4
        for (int i = 0; i < 16; ++i) {
          const int kf = kc*4 + (i & 3) + (i >> 2)*64;  // strided over 256 f4
          acc += dot4(s4[kf], w4[kf]);
        }
        acc += __shfl_down(acc, 8, 16);
        acc += __shfl_down(acc, 4, 16);
        acc += __shfl_down(acc, 2, 16);
        acc += __shfl_down(acc, 1, 16);
        if (kc == 0) qv[b*ATT + a] = acc;
      } else {
        const int m = (part - 8)*11 + ol;         // 0..87, need 0..80
        if (ol < 11 && m < 81) {
          const float* wrow = (m < NMEL) ? (proj_w + m*(HH+EE)) : stop_w;
          const float4* w4 = (const float4*)wrow;
          float acc = 0.0f;
          #pragma unroll 4
          for (int i = 0; i < 24; ++i) {
            const int kf = kc + 16*i;             // 384 float4 = 1536 floats
            acc += dot4(s4[kf], w4[kf]);
          }
          acc += __shfl_down(acc, 8, 16);
          acc += __shfl_down(acc, 4, 16);
          acc += __shfl_down(acc, 2, 16);
          acc += __shfl_down(acc, 1, 16);
          if (kc == 0) {
            if (m < NMEL) out[(b*TD + t)*NMEL + m] = acc + proj_b[m];
            else          out[NB*TD*NMEL + b*TD + t] = acc + stop_b[0];
          }
        }
      }
    }
    lbar(bar, b_grp);
  }
}

extern "C" void kernel_launch(void* const* d_in, const int* in_sizes, int n_in,
                              void* d_out, int out_size, void* d_ws, size_t ws_size,
                              hipStream_t stream) {
  (void)in_sizes; (void)n_in; (void)out_size; (void)ws_size;
  const float* enc         = (const float*)d_in[0];
  const float* mels        = (const float*)d_in[1];
  const float* enc_proj_w  = (const float*)d_in[2];
  const float* lstm_proj_w = (const float*)d_in[3];
  const float* loc_conv_w  = (const float*)d_in[4];
  const float* loc_conv_b  = (const float*)d_in[5];
  const float* loc_dense_w = (const float*)d_in[6];
  const float* loc_dense_b = (const float*)d_in[7];
  const float* e_w         = (const float*)d_in[8];
  const float* e_b         = (const float*)d_in[9];
  const float* prenet1_w   = (const float*)d_in[10];
  const float* prenet2_w   = (const float*)d_in[11];
  const float* w_ih0       = (const float*)d_in[12];
  const float* b_ih0       = (const float*)d_in[14];
  const float* b_hh0       = (const float*)d_in[15];
  const float* w_ih1       = (const float*)d_in[16];
  const float* b_ih1       = (const float*)d_in[18];
  const float* b_hh1       = (const float*)d_in[19];
  const float* proj_w      = (const float*)d_in[20];
  const float* proj_b      = (const float*)d_in[21];
  const float* stop_w      = (const float*)d_in[22];
  const float* stop_b      = (const float*)d_in[23];
  const int*   text_len    = (const int*)d_in[24];
  float* ws  = (float*)d_ws;
  float* out = (float*)d_out;

  static int attr_set = 0;
  if (!attr_set) {
    hipFuncSetAttribute((const void*)k_main,
                        hipFuncAttributeMaxDynamicSharedMemorySize, DYN_BYTES);
    attr_set = 1;
  }

  k_init<<<dim3(1), dim3(256), 0, stream>>>(ws);
  k_prenet<<<dim3(TD*NB), dim3(256), 0, stream>>>(mels, prenet1_w, prenet2_w, ws + OFF_X2);
  k_procenc<<<dim3(NB*TE), dim3(128), 0, stream>>>(enc, enc_proj_w, ws + OFF_PE);

  k_main<<<dim3(256), dim3(256), DYN_BYTES, stream>>>(
      enc, lstm_proj_w, loc_conv_w, loc_conv_b, loc_dense_w, loc_dense_b,
      e_w, e_b, w_ih0, b_ih0, b_hh0, w_ih1, b_ih1, b_hh1,
      proj_w, proj_b, stop_w, stop_b, text_len, ws, out);
}